// Round 11
// baseline (149.603 us; speedup 1.0000x reference)
//
#include <hip/hip_runtime.h>

#define K_BINS 1025
#define T_LEN  2000
#define NF     128
#define TQ     500    // t per block (2000 = 4*500, no tail)
#define ROWQ   500    // float4 per full k-row
#define WSTEPS 12     // max support span: bw*(s0+s1) ~= 11.36 bins -> <= 12 rows

__device__ __forceinline__ float softplusf(float x) {
    // matches jax.nn.softplus = max(x,0) + log1p(exp(-|x|))
    return fmaxf(x, 0.0f) + log1pf(expf(-fabsf(x)));
}

// out[b2][t][4*bp + w] = sum_k w_f(k) * spec[bp][k][t],  f = b2 + 32*w
// Block = (bp-quad q, b2-quad B, t-quarter th). 1024 thr = 16 waves (w,p).
// Wave (w,p): filters f = 4B+32w+i (i=0..3) for bp = 4q+p, t-chunk of 500.
// Fixed 12-step fully-unrolled branch-free walk per filter (uniform width
// => span <= 12 rows): no runtime cursors, no v=n copy chains -> compiler
// can hoist loads across steps (R6-R9 were stuck at ~1.4 us/row = serial
// miss latency). Pad steps: address clamps to row 1024, weight masked to 0
// for k >= K_BINS (R10's bug: triangle extends past the last bin for high
// filters, so the weight alone does NOT self-mask at the top boundary).
// Epilogue: LDS [512][17] transpose -> full 64 B line float4 stores.
__global__ __launch_bounds__(1024) void fb_fused(
        const float* __restrict__ spec,
        const float* __restrict__ cf,
        const float* __restrict__ bwv,
        const float* __restrict__ fs,
        float*       __restrict__ out) {
    const int q    = blockIdx.x;   // bp-quad 0..7 (id%8 -> XCD q)
    const int B    = blockIdx.y;   // b2-quad 0..7
    const int th   = blockIdx.z;   // t-quarter 0..3
    const int tid  = threadIdx.x;
    const int lane = tid & 63;
    const int wid  = tid >> 6;     // 0..15
    const int w    = wid >> 2;     // filter band 0..3
    const int p    = wid & 3;      // bp-local 0..3
    const int bp   = 4 * q + p;
    const int t0   = TQ * th;
    const bool ok1 = lane < (TQ / 4 - 64);       // second float4 live (lane<61)
    const int  li1 = min(64 + lane, TQ / 4 - 1); // clamped to chunk: in-bounds,
                                                 // dead lanes discarded in epilogue

    const float4* base4 =
        (const float4*)(spec + (size_t)bp * (K_BINS * (size_t)T_LEN) + t0);

    float4 acc[4][2];              // [filter i][t-half]
#pragma unroll
    for (int i = 0; i < 4; ++i) {
        acc[i][0] = make_float4(0.f, 0.f, 0.f, 0.f);
        acc[i][1] = make_float4(0.f, 0.f, 0.f, 0.f);
    }

#pragma unroll
    for (int i = 0; i < 4; ++i) {
        const int f = 4 * B + 32 * w + i;
        float c  = cf[f];
        float bw = softplusf(bwv[f]) + 0.001f;
        float s0 = softplusf(fs[2 * f])     + 0.1f;
        float s1 = softplusf(fs[2 * f + 1]) + 0.1f;
        float left  = c - bw * s0;
        float right = c + bw * s1;
        float ic = 1.0f / (c - left + 1e-8f);
        float ir = 1.0f / (right - c + 1e-8f);
        float mA = -left * ic;              // rise = fk*ic + mA
        float Bf = fmaf(c, ir, 1.0f);       // fall = -fk*ir + Bf
        const int klo = max(0, (int)ceilf(left));

#pragma unroll
        for (int m = 0; m < WSTEPS; ++m) {
            const int k  = klo + m;
            const int kc = min(k, K_BINS - 1);          // safe address
            const float4* rp = base4 + (size_t)kc * ROWQ;
            float4 v0 = rp[lane];
            float4 v1 = rp[li1];
            float fk  = (float)k;                       // UNclamped for weight
            float wg  = fmaxf(0.0f,
                              fminf(fmaf(fk, ic, mA), fmaf(-fk, ir, Bf)));
            wg = (k < K_BINS) ? wg : 0.0f;              // top-boundary mask
            acc[i][0].x = fmaf(wg, v0.x, acc[i][0].x);
            acc[i][0].y = fmaf(wg, v0.y, acc[i][0].y);
            acc[i][0].z = fmaf(wg, v0.z, acc[i][0].z);
            acc[i][0].w = fmaf(wg, v0.w, acc[i][0].w);
            acc[i][1].x = fmaf(wg, v1.x, acc[i][1].x);
            acc[i][1].y = fmaf(wg, v1.y, acc[i][1].y);
            acc[i][1].z = fmaf(wg, v1.z, acc[i][1].z);
            acc[i][1].w = fmaf(wg, v1.w, acc[i][1].w);
        }
    }

    // Epilogue: per filter i, transpose via LDS, store full 64 B lines.
    __shared__ float tile[512][17];
#pragma unroll
    for (int i = 0; i < 4; ++i) {
        __syncthreads();               // protect tile reuse
        {
            const int col = 4 * p + w; // f2 - 16q
            const int rb  = 4 * lane;
#pragma unroll
            for (int r = 0; r < 4; ++r)
                tile[rb + r][col] = (&acc[i][0].x)[r];
            if (ok1) {
#pragma unroll
                for (int r = 0; r < 4; ++r)
                    tile[256 + rb + r][col] = (&acc[i][1].x)[r];
            }
        }
        __syncthreads();
        const int b2 = 4 * B + i;
        const int c4 = tid & 3;
#pragma unroll
        for (int rr = 0; rr < 2; ++rr) {
            int tl = 256 * rr + (tid >> 2);
            if (tl < TQ) {
                float4 v = make_float4(tile[tl][4 * c4 + 0], tile[tl][4 * c4 + 1],
                                       tile[tl][4 * c4 + 2], tile[tl][4 * c4 + 3]);
                *reinterpret_cast<float4*>(
                    out + ((size_t)b2 * T_LEN + t0 + tl) * NF + 16 * q + 4 * c4) = v;
            }
        }
    }
}

extern "C" void kernel_launch(void* const* d_in, const int* in_sizes, int n_in,
                              void* d_out, int out_size, void* d_ws, size_t ws_size,
                              hipStream_t stream) {
    const float* spec = (const float*)d_in[0];   // (32, 1025, 2000) f32
    const float* cf   = (const float*)d_in[1];   // (128,)
    const float* bwv  = (const float*)d_in[2];   // (128,)
    const float* fs   = (const float*)d_in[3];   // (128, 2)
    float* out = (float*)d_out;                  // (32, 2000, 128) f32

    fb_fused<<<dim3(8, 8, 4), 1024, 0, stream>>>(spec, cf, bwv, fs, out);
}